// Round 5
// baseline (447.783 us; speedup 1.0000x reference)
//
#include <hip/hip_runtime.h>

#define SB 2048
#define DM 1024
#define N3 3072
#define NB 4

typedef short bf16x8 __attribute__((ext_vector_type(8)));
typedef float f32x4 __attribute__((ext_vector_type(4)));
typedef unsigned short u16;

#define MFMA16(a, b, c) __builtin_amdgcn_mfma_f32_16x16x32_bf16(a, b, c, 0, 0, 0)

typedef const __attribute__((address_space(1))) unsigned int* gptr_t;
typedef __attribute__((address_space(3))) unsigned int* lptr_t;

__device__ __forceinline__ u16 f2bf(float x) {
  union { float f; unsigned u; } c; c.f = x;
  unsigned r = c.u + 0x7FFFu + ((c.u >> 16) & 1u);
  return (u16)(r >> 16);
}

// ---------------- 1) x fp32 -> bf16 ----------------
__global__ void k_cvt_x(const float* __restrict__ x, u16* __restrict__ xb, int n4) {
  int i = blockIdx.x * blockDim.x + threadIdx.x;
  if (i >= n4) return;
  float4 v = ((const float4*)x)[i];
  ushort4 o;
  o.x = f2bf(v.x); o.y = f2bf(v.y); o.z = f2bf(v.z); o.w = f2bf(v.w);
  ((ushort4*)xb)[i] = o;
}

// ---------------- 2) W [1024][3072] f32 -> Wt [3072][1024] bf16 ----------------
__global__ void k_cvt_wt(const float* __restrict__ W, u16* __restrict__ Wt) {
  __shared__ float t[32][33];
  int n0 = blockIdx.x * 32;
  int k0 = blockIdx.y * 32;
  int tx = threadIdx.x & 31, ty = threadIdx.x >> 5;
#pragma unroll
  for (int r = 0; r < 4; ++r)
    t[ty + r * 8][tx] = W[(size_t)(k0 + ty + r * 8) * N3 + n0 + tx];
  __syncthreads();
#pragma unroll
  for (int r = 0; r < 4; ++r)
    Wt[(size_t)(n0 + ty + r * 8) * DM + k0 + tx] = f2bf(t[tx][ty + r * 8]);
}

// ---------------- 3) GEMM: qkv[8192][3072] = xb[8192][1024] @ Wt^T ----------------
// Double-buffered LDS (parity) so iteration i+1's global_load_lds writes never
// target the buffer read in iteration i (cross-iteration WAR hardening).
__global__ __launch_bounds__(256, 2) void k_gemm(const u16* __restrict__ xb,
                                                 const u16* __restrict__ wt,
                                                 u16* __restrict__ qkv) {
  __shared__ u16 As[2][128 * 32];
  __shared__ u16 Bs[2][128 * 32];
  int mt = blockIdx.x / 24, nt = blockIdx.x % 24;
  int m0 = mt * 128, n0 = nt * 128;
  int tid = threadIdx.x, lane = tid & 63, wid = tid >> 6;
  int lr = lane & 15, lg = lane >> 4;
  int wm = (wid >> 1) * 64, wn = (wid & 1) * 64;
  int ca = lane >> 2;          // row within 16-row staging chunk
  int cb = (lane & 3) * 8;     // col element within row
  f32x4 acc[4][4] = {};
  int p = 0;
  for (int kk = 0; kk < 1024; kk += 32) {
#pragma unroll
    for (int j = 0; j < 2; ++j) {
      int chunk = wid * 2 + j;
      const u16* ga = xb + (size_t)(m0 + chunk * 16 + ca) * 1024 + kk + cb;
      const u16* gb = wt + (size_t)(n0 + chunk * 16 + ca) * 1024 + kk + cb;
      __builtin_amdgcn_global_load_lds((gptr_t)(const void*)ga, (lptr_t)(void*)&As[p][chunk * 512], 16, 0, 0);
      __builtin_amdgcn_global_load_lds((gptr_t)(const void*)gb, (lptr_t)(void*)&Bs[p][chunk * 512], 16, 0, 0);
    }
    __syncthreads();
    bf16x8 af[4], bff[4];
#pragma unroll
    for (int i = 0; i < 4; ++i) af[i] = *(const bf16x8*)&As[p][(wm + i * 16 + lr) * 32 + lg * 8];
#pragma unroll
    for (int j = 0; j < 4; ++j) bff[j] = *(const bf16x8*)&Bs[p][(wn + j * 16 + lr) * 32 + lg * 8];
#pragma unroll
    for (int i = 0; i < 4; ++i)
#pragma unroll
      for (int j = 0; j < 4; ++j)
        acc[i][j] = MFMA16(af[i], bff[j], acc[i][j]);
    __syncthreads();
    p ^= 1;
  }
#pragma unroll
  for (int i = 0; i < 4; ++i)
#pragma unroll
    for (int j = 0; j < 4; ++j)
#pragma unroll
      for (int r = 0; r < 4; ++r)
        qkv[(size_t)(m0 + wm + i * 16 + lg * 4 + r) * N3 + n0 + wn + j * 16 + lr] = f2bf(acc[i][j][r]);
}

// ---------------- 4) V transpose: qkv[:, 2048:3072] -> vt[b][d][s] ----------------
__global__ void k_vt(const u16* __restrict__ qkv, u16* __restrict__ vt) {
  __shared__ u16 t[32][34];
  int bx = blockIdx.x;
  int b = bx >> 11, rem = bx & 2047;
  int s0 = (rem >> 5) * 32, d0 = (rem & 31) * 32;
  int tx = threadIdx.x & 31, ty = threadIdx.x >> 5;
#pragma unroll
  for (int r = 0; r < 4; ++r)
    t[ty + r * 8][tx] = qkv[(size_t)(b * SB + s0 + ty + r * 8) * N3 + 2048 + d0 + tx];
  __syncthreads();
#pragma unroll
  for (int r = 0; r < 4; ++r)
    vt[(size_t)(b * DM + d0 + ty + r * 8) * SB + s0 + tx] = t[tx][ty + r * 8];
}

// ---------------- 5) flash attention (anti-causal: key >= query) ----------------
// S/P/sc parity double-buffered: iteration i+1 writes buffer ib^1 relative to
// what iteration i's readers used -> cross-iteration LDS WAR distance >= 3 barriers.
__global__ __launch_bounds__(512, 2) void k_attn(const u16* __restrict__ qkv,
                                                 const u16* __restrict__ vt,
                                                 float* __restrict__ out) {
  __shared__ float S_lds[2][16][132];
  __shared__ u16 P_lds[2][16][136];
  __shared__ float m_lds[16], l_lds[16];
  __shared__ float sc_lds[2][16];
  int tid = threadIdx.x, lane = tid & 63, wid = tid >> 6;
  int lr = lane & 15, lg = lane >> 4;
  int b = blockIdx.x >> 6, pr = blockIdx.x & 63;

  for (int ti = 0; ti < 2; ++ti) {
    int tile = ti ? (127 - pr) : pr;
    int q0 = tile * 16;

    // Q fragments resident in registers for the whole key loop
    bf16x8 qf[32];
    const u16* qb = qkv + (size_t)(b * SB + q0 + lr) * N3;
#pragma unroll
    for (int dc = 0; dc < 32; ++dc) qf[dc] = *(const bf16x8*)(qb + dc * 32 + lg * 8);

    f32x4 o[8] = {};
    __syncthreads();   // protect m/l from previous tile's readers
    if (tid < 16) { m_lds[tid] = -1e30f; l_lds[tid] = 0.f; }
    __syncthreads();

    int ib = 0;
    for (int k0 = q0 & ~127; k0 < SB; k0 += 128) {
      // ---- QK^T for this wave's 16 keys, full D=1024 ----
      f32x4 s = {};
      const u16* kb = qkv + (size_t)(b * SB + k0 + wid * 16 + lr) * N3 + 1024;
#pragma unroll
      for (int dc = 0; dc < 32; ++dc) {
        bf16x8 kf = *(const bf16x8*)(kb + dc * 32 + lg * 8);
        s = MFMA16(qf[dc], kf, s);
      }
      int kcol = k0 + wid * 16 + lr;
#pragma unroll
      for (int r = 0; r < 4; ++r) {
        float v = s[r] * 0.03125f;                 // 1/sqrt(1024)
        if (kcol < q0 + lg * 4 + r) v = -1e30f;    // keep key >= query
        S_lds[ib][lg * 4 + r][wid * 16 + lr] = v;
      }
      __syncthreads();

      // ---- online softmax over the 128-key tile (32 threads per row) ----
      {
        int row = tid >> 5, c4 = (tid & 31) * 4;
        float s0 = S_lds[ib][row][c4], s1 = S_lds[ib][row][c4 + 1];
        float s2 = S_lds[ib][row][c4 + 2], s3 = S_lds[ib][row][c4 + 3];
        float mx = fmaxf(fmaxf(s0, s1), fmaxf(s2, s3));
#pragma unroll
        for (int off = 16; off; off >>= 1) mx = fmaxf(mx, __shfl_xor(mx, off, 32));
        float mold = m_lds[row];
        float mnew = fmaxf(mold, mx);
        float p0 = __expf(s0 - mnew), p1 = __expf(s1 - mnew);
        float p2 = __expf(s2 - mnew), p3 = __expf(s3 - mnew);
        float sum = (p0 + p1) + (p2 + p3);
#pragma unroll
        for (int off = 16; off; off >>= 1) sum += __shfl_xor(sum, off, 32);
        P_lds[ib][row][c4] = f2bf(p0);
        P_lds[ib][row][c4 + 1] = f2bf(p1);
        P_lds[ib][row][c4 + 2] = f2bf(p2);
        P_lds[ib][row][c4 + 3] = f2bf(p3);
        if ((tid & 31) == 0) {
          float sc = __expf(mold - mnew);
          sc_lds[ib][row] = sc;
          m_lds[row] = mnew;
          l_lds[row] = l_lds[row] * sc + sum;
        }
      }
      __syncthreads();

      // ---- rescale O, then PV ----
      float f0 = sc_lds[ib][lg * 4], f1 = sc_lds[ib][lg * 4 + 1];
      float f2v = sc_lds[ib][lg * 4 + 2], f3 = sc_lds[ib][lg * 4 + 3];
#pragma unroll
      for (int cf = 0; cf < 8; ++cf) {
        o[cf][0] *= f0; o[cf][1] *= f1; o[cf][2] *= f2v; o[cf][3] *= f3;
      }
#pragma unroll
      for (int kc = 0; kc < 4; ++kc) {
        bf16x8 pf = *(const bf16x8*)&P_lds[ib][lr][kc * 32 + lg * 8];
#pragma unroll
        for (int cf = 0; cf < 8; ++cf) {
          const u16* vb = vt + (size_t)(b * DM + wid * 128 + cf * 16 + lr) * SB + k0 + kc * 32 + lg * 8;
          bf16x8 vf = *(const bf16x8*)vb;
          o[cf] = MFMA16(pf, vf, o[cf]);
        }
      }
      __syncthreads();
      ib ^= 1;
    }

    // ---- finalize: divide by softmax denominator, write fp32 ----
    float i0 = 1.f / l_lds[lg * 4], i1 = 1.f / l_lds[lg * 4 + 1];
    float i2 = 1.f / l_lds[lg * 4 + 2], i3 = 1.f / l_lds[lg * 4 + 3];
#pragma unroll
    for (int cf = 0; cf < 8; ++cf) {
      size_t ob = (size_t)(b * SB + q0 + lg * 4) * DM + wid * 128 + cf * 16 + lr;
      out[ob] = o[cf][0] * i0;
      out[ob + DM] = o[cf][1] * i1;
      out[ob + 2 * DM] = o[cf][2] * i2;
      out[ob + 3 * DM] = o[cf][3] * i3;
    }
  }
}

extern "C" void kernel_launch(void* const* d_in, const int* in_sizes, int n_in,
                              void* d_out, int out_size, void* d_ws, size_t ws_size,
                              hipStream_t stream) {
  const float* x = (const float*)d_in[0];
  const float* W = (const float*)d_in[1];
  float* out = (float*)d_out;
  char* ws = (char*)d_ws;
  u16* xb  = (u16*)(ws);                 // 16 MB  : x bf16 [8192][1024]
  u16* wt  = (u16*)(ws + 16777216);      // 6 MB   : W^T bf16 [3072][1024]
  u16* qkv = (u16*)(ws + 23068672);      // 48 MB  : qkv bf16 [8192][3072]
  u16* vt  = (u16*)(ws + 73400320);      // 16 MB  : V^T bf16 [4][1024][2048]

  k_cvt_x<<<8192, 256, 0, stream>>>(x, xb, 2097152);
  dim3 gw(96, 32);
  k_cvt_wt<<<gw, 256, 0, stream>>>(W, wt);
  k_gemm<<<1536, 256, 0, stream>>>(xb, wt, qkv);
  k_vt<<<8192, 256, 0, stream>>>(qkv, vt);
  k_attn<<<256, 512, 0, stream>>>(qkv, vt, out);
}

// Round 6
// 344.486 us; speedup vs baseline: 1.2999x; 1.2999x over previous
//
#include <hip/hip_runtime.h>

#define SB 2048
#define DM 1024
#define N3 3072
#define NB 4

typedef short bf16x8 __attribute__((ext_vector_type(8)));
typedef float f32x4 __attribute__((ext_vector_type(4)));
typedef unsigned short u16;

#define MFMA16(a, b, c) __builtin_amdgcn_mfma_f32_16x16x32_bf16(a, b, c, 0, 0, 0)

typedef const __attribute__((address_space(1))) unsigned int* gptr_t;
typedef __attribute__((address_space(3))) unsigned int* lptr_t;

__device__ __forceinline__ u16 f2bf(float x) {
  union { float f; unsigned u; } c; c.f = x;
  unsigned r = c.u + 0x7FFFu + ((c.u >> 16) & 1u);
  return (u16)(r >> 16);
}

// ---------------- 1) x fp32 -> bf16 ----------------
__global__ void k_cvt_x(const float* __restrict__ x, u16* __restrict__ xb, int n4) {
  int i = blockIdx.x * blockDim.x + threadIdx.x;
  if (i >= n4) return;
  float4 v = ((const float4*)x)[i];
  ushort4 o;
  o.x = f2bf(v.x); o.y = f2bf(v.y); o.z = f2bf(v.z); o.w = f2bf(v.w);
  ((ushort4*)xb)[i] = o;
}

// ---------------- 2) W [1024][3072] f32 -> Wt [3072][1024] bf16 ----------------
__global__ void k_cvt_wt(const float* __restrict__ W, u16* __restrict__ Wt) {
  __shared__ float t[32][33];
  int n0 = blockIdx.x * 32;
  int k0 = blockIdx.y * 32;
  int tx = threadIdx.x & 31, ty = threadIdx.x >> 5;
#pragma unroll
  for (int r = 0; r < 4; ++r)
    t[ty + r * 8][tx] = W[(size_t)(k0 + ty + r * 8) * N3 + n0 + tx];
  __syncthreads();
#pragma unroll
  for (int r = 0; r < 4; ++r)
    Wt[(size_t)(n0 + ty + r * 8) * DM + k0 + tx] = f2bf(t[tx][ty + r * 8]);
}

// ---------------- 3) GEMM: qkv[8192][3072] = xb[8192][1024] @ Wt^T ----------------
__global__ __launch_bounds__(256, 2) void k_gemm(const u16* __restrict__ xb,
                                                 const u16* __restrict__ wt,
                                                 u16* __restrict__ qkv) {
  __shared__ u16 As[2][128 * 32];
  __shared__ u16 Bs[2][128 * 32];
  int mt = blockIdx.x / 24, nt = blockIdx.x % 24;
  int m0 = mt * 128, n0 = nt * 128;
  int tid = threadIdx.x, lane = tid & 63, wid = tid >> 6;
  int lr = lane & 15, lg = lane >> 4;
  int wm = (wid >> 1) * 64, wn = (wid & 1) * 64;
  int ca = lane >> 2;
  int cb = (lane & 3) * 8;
  f32x4 acc[4][4] = {};
  int p = 0;
  for (int kk = 0; kk < 1024; kk += 32) {
#pragma unroll
    for (int j = 0; j < 2; ++j) {
      int chunk = wid * 2 + j;
      const u16* ga = xb + (size_t)(m0 + chunk * 16 + ca) * 1024 + kk + cb;
      const u16* gb = wt + (size_t)(n0 + chunk * 16 + ca) * 1024 + kk + cb;
      __builtin_amdgcn_global_load_lds((gptr_t)(const void*)ga, (lptr_t)(void*)&As[p][chunk * 512], 16, 0, 0);
      __builtin_amdgcn_global_load_lds((gptr_t)(const void*)gb, (lptr_t)(void*)&Bs[p][chunk * 512], 16, 0, 0);
    }
    __syncthreads();
    bf16x8 af[4], bff[4];
#pragma unroll
    for (int i = 0; i < 4; ++i) af[i] = *(const bf16x8*)&As[p][(wm + i * 16 + lr) * 32 + lg * 8];
#pragma unroll
    for (int j = 0; j < 4; ++j) bff[j] = *(const bf16x8*)&Bs[p][(wn + j * 16 + lr) * 32 + lg * 8];
#pragma unroll
    for (int i = 0; i < 4; ++i)
#pragma unroll
      for (int j = 0; j < 4; ++j)
        acc[i][j] = MFMA16(af[i], bff[j], acc[i][j]);
    __syncthreads();
    p ^= 1;
  }
#pragma unroll
  for (int i = 0; i < 4; ++i)
#pragma unroll
    for (int j = 0; j < 4; ++j)
#pragma unroll
      for (int r = 0; r < 4; ++r)
        qkv[(size_t)(m0 + wm + i * 16 + lg * 4 + r) * N3 + n0 + wn + j * 16 + lr] = f2bf(acc[i][j][r]);
}

// ---------------- 4) V transpose: qkv[:, 2048:3072] -> vt[b][d][s] ----------------
__global__ void k_vt(const u16* __restrict__ qkv, u16* __restrict__ vt) {
  __shared__ u16 t[32][34];
  int bx = blockIdx.x;
  int b = bx >> 11, rem = bx & 2047;
  int s0 = (rem >> 5) * 32, d0 = (rem & 31) * 32;
  int tx = threadIdx.x & 31, ty = threadIdx.x >> 5;
#pragma unroll
  for (int r = 0; r < 4; ++r)
    t[ty + r * 8][tx] = qkv[(size_t)(b * SB + s0 + ty + r * 8) * N3 + 2048 + d0 + tx];
  __syncthreads();
#pragma unroll
  for (int r = 0; r < 4; ++r)
    vt[(size_t)(b * DM + d0 + ty + r * 8) * SB + s0 + tx] = t[tx][ty + r * 8];
}

// ---------------- 5) flash attention v2 (anti-causal: key >= query) ----------------
// Changes vs v1: Q staged in LDS (XOR-swizzled) instead of 128 VGPRs of qf;
// 8-deep register ring prefetch for K and V global loads; one 16-row q-tile
// per block, grid 512 (2 blocks/CU), LPT dispatch order (tile = bid>>2).
__global__ __launch_bounds__(512, 2) void k_attn(const u16* __restrict__ qkv,
                                                 const u16* __restrict__ vt,
                                                 float* __restrict__ out) {
  __shared__ u16 Q_lds[16 * 1024];        // 32 KB, swizzled: byte ^= (row&7)<<4
  __shared__ float S_lds[2][16][132];
  __shared__ u16 P_lds[2][16][136];
  __shared__ float m_lds[16], l_lds[16];
  __shared__ float sc_lds[2][16];
  int tid = threadIdx.x, lane = tid & 63, wid = tid >> 6;
  int lr = lane & 15, lg = lane >> 4;
  int bid = blockIdx.x;
  int b = bid & 3;            // batch
  int tile = bid >> 2;        // 0..127, tile 0 = most work, launches first (LPT)
  int q0 = tile * 16;

  // ---- stage Q tile [16][1024] into LDS with row-XOR swizzle ----
  {
    int row = tid >> 5;                 // 0..15
    int cu = (tid & 31) * 32;           // u16 col, 32 per thread
    const u16* gq = qkv + (size_t)(b * SB + q0 + row) * N3 + cu;
#pragma unroll
    for (int j = 0; j < 4; ++j) {
      bf16x8 v = *(const bf16x8*)(gq + j * 8);
      int bytecol = cu * 2 + j * 16;
      int swz = bytecol ^ ((row & 7) << 4);
      *(bf16x8*)&Q_lds[row * 1024 + (swz >> 1)] = v;
    }
  }
  if (tid < 16) { m_lds[tid] = -1e30f; l_lds[tid] = 0.f; }
  __syncthreads();

  f32x4 o[8] = {};
  int ib = 0;
  for (int k0 = q0 & ~127; k0 < SB; k0 += 128) {
    // ---- QK^T: this wave's 16 keys, full D=1024, K ring-prefetched ----
    const u16* kb = qkv + (size_t)(b * SB + k0 + wid * 16 + lr) * N3 + 1024;
    bf16x8 ring[8];
#pragma unroll
    for (int i = 0; i < 8; ++i) ring[i] = *(const bf16x8*)(kb + i * 32 + lg * 8);
    f32x4 s = {};
#pragma unroll
    for (int dc = 0; dc < 32; ++dc) {
      bf16x8 kf = ring[dc & 7];
      int swz = (dc * 64 + lg * 16) ^ ((lr & 7) << 4);
      bf16x8 aq = *(const bf16x8*)&Q_lds[lr * 1024 + (swz >> 1)];
      if (dc < 24) ring[dc & 7] = *(const bf16x8*)(kb + (dc + 8) * 32 + lg * 8);
      s = MFMA16(aq, kf, s);
    }
    int kcol = k0 + wid * 16 + lr;
#pragma unroll
    for (int r = 0; r < 4; ++r) {
      float v = s[r] * 0.03125f;                 // 1/sqrt(1024)
      if (kcol < q0 + lg * 4 + r) v = -1e30f;    // keep key >= query
      S_lds[ib][lg * 4 + r][wid * 16 + lr] = v;
    }
    __syncthreads();

    // ---- online softmax over the 128-key tile (32 threads per row) ----
    {
      int row = tid >> 5, c4 = (tid & 31) * 4;
      float s0 = S_lds[ib][row][c4], s1 = S_lds[ib][row][c4 + 1];
      float s2 = S_lds[ib][row][c4 + 2], s3 = S_lds[ib][row][c4 + 3];
      float mx = fmaxf(fmaxf(s0, s1), fmaxf(s2, s3));
#pragma unroll
      for (int off = 16; off; off >>= 1) mx = fmaxf(mx, __shfl_xor(mx, off, 32));
      float mold = m_lds[row];
      float mnew = fmaxf(mold, mx);
      float p0 = __expf(s0 - mnew), p1 = __expf(s1 - mnew);
      float p2 = __expf(s2 - mnew), p3 = __expf(s3 - mnew);
      float sum = (p0 + p1) + (p2 + p3);
#pragma unroll
      for (int off = 16; off; off >>= 1) sum += __shfl_xor(sum, off, 32);
      P_lds[ib][row][c4] = f2bf(p0);
      P_lds[ib][row][c4 + 1] = f2bf(p1);
      P_lds[ib][row][c4 + 2] = f2bf(p2);
      P_lds[ib][row][c4 + 3] = f2bf(p3);
      if ((tid & 31) == 0) {
        float sc = __expf(mold - mnew);
        sc_lds[ib][row] = sc;
        m_lds[row] = mnew;
        l_lds[row] = l_lds[row] * sc + sum;
      }
    }
    __syncthreads();

    // ---- rescale O, then PV with V ring prefetch ----
    float f0 = sc_lds[ib][lg * 4], f1 = sc_lds[ib][lg * 4 + 1];
    float f2v = sc_lds[ib][lg * 4 + 2], f3 = sc_lds[ib][lg * 4 + 3];
#pragma unroll
    for (int cf = 0; cf < 8; ++cf) {
      o[cf][0] *= f0; o[cf][1] *= f1; o[cf][2] *= f2v; o[cf][3] *= f3;
    }
    const u16* vbase = vt + (size_t)(b * DM + wid * 128 + lr) * SB + k0 + lg * 8;
    // flat idx = kc*8 + cf; addr(kc,cf) = vbase + cf*16*SB + kc*32
    bf16x8 vring[8];
#pragma unroll
    for (int i = 0; i < 8; ++i) vring[i] = *(const bf16x8*)(vbase + (size_t)i * 16 * SB);
#pragma unroll
    for (int kc = 0; kc < 4; ++kc) {
      bf16x8 pf = *(const bf16x8*)&P_lds[ib][lr][kc * 32 + lg * 8];
#pragma unroll
      for (int cf = 0; cf < 8; ++cf) {
        bf16x8 vf = vring[cf];
        int nidx = kc * 8 + cf + 8;
        if (nidx < 32)
          vring[cf] = *(const bf16x8*)(vbase + (size_t)(nidx & 7) * 16 * SB + (nidx >> 3) * 32);
        o[cf] = MFMA16(pf, vf, o[cf]);
      }
    }
    __syncthreads();
    ib ^= 1;
  }

  // ---- finalize: divide by softmax denominator, write fp32 ----
  float i0 = 1.f / l_lds[lg * 4], i1 = 1.f / l_lds[lg * 4 + 1];
  float i2 = 1.f / l_lds[lg * 4 + 2], i3 = 1.f / l_lds[lg * 4 + 3];
#pragma unroll
  for (int cf = 0; cf < 8; ++cf) {
    size_t ob = (size_t)(b * SB + q0 + lg * 4) * DM + wid * 128 + cf * 16 + lr;
    out[ob] = o[cf][0] * i0;
    out[ob + DM] = o[cf][1] * i1;
    out[ob + 2 * DM] = o[cf][2] * i2;
    out[ob + 3 * DM] = o[cf][3] * i3;
  }
}

extern "C" void kernel_launch(void* const* d_in, const int* in_sizes, int n_in,
                              void* d_out, int out_size, void* d_ws, size_t ws_size,
                              hipStream_t stream) {
  const float* x = (const float*)d_in[0];
  const float* W = (const float*)d_in[1];
  float* out = (float*)d_out;
  char* ws = (char*)d_ws;
  u16* xb  = (u16*)(ws);                 // 16 MB  : x bf16 [8192][1024]
  u16* wt  = (u16*)(ws + 16777216);      // 6 MB   : W^T bf16 [3072][1024]
  u16* qkv = (u16*)(ws + 23068672);      // 48 MB  : qkv bf16 [8192][3072]
  u16* vt  = (u16*)(ws + 73400320);      // 16 MB  : V^T bf16 [4][1024][2048]

  k_cvt_x<<<8192, 256, 0, stream>>>(x, xb, 2097152);
  dim3 gw(96, 32);
  k_cvt_wt<<<gw, 256, 0, stream>>>(W, wt);
  k_gemm<<<1536, 256, 0, stream>>>(xb, wt, qkv);
  k_vt<<<8192, 256, 0, stream>>>(qkv, vt);
  k_attn<<<512, 512, 0, stream>>>(qkv, vt, out);
}

// Round 7
// 167.603 us; speedup vs baseline: 2.6717x; 2.0554x over previous
//
#include <hip/hip_runtime.h>

#define SB 2048
#define DM 1024
#define N3 3072

typedef short bf16x8 __attribute__((ext_vector_type(8)));
typedef float f32x4 __attribute__((ext_vector_type(4)));
typedef unsigned short u16;

#define MFMA16(a, b, c) __builtin_amdgcn_mfma_f32_16x16x32_bf16(a, b, c, 0, 0, 0)

typedef const __attribute__((address_space(1))) unsigned int* gptr_t;
typedef __attribute__((address_space(3))) unsigned int* lptr_t;

__device__ __forceinline__ u16 f2bf(float x) {
  union { float f; unsigned u; } c; c.f = x;
  unsigned r = c.u + 0x7FFFu + ((c.u >> 16) & 1u);
  return (u16)(r >> 16);
}
__device__ __forceinline__ float bf2f(u16 x) {
  union { unsigned u; float f; } c; c.u = ((unsigned)x) << 16;
  return c.f;
}

// ---------------- 1) x fp32 -> bf16 ----------------
__global__ void k_cvt_x(const float* __restrict__ x, u16* __restrict__ xb, int n4) {
  int i = blockIdx.x * blockDim.x + threadIdx.x;
  if (i >= n4) return;
  float4 v = ((const float4*)x)[i];
  ushort4 o;
  o.x = f2bf(v.x); o.y = f2bf(v.y); o.z = f2bf(v.z); o.w = f2bf(v.w);
  ((ushort4*)xb)[i] = o;
}

// ---------------- 2) W [1024][3072] f32 -> Wt [3072][1024] bf16 ----------------
__global__ void k_cvt_wt(const float* __restrict__ W, u16* __restrict__ Wt) {
  __shared__ float t[32][33];
  int n0 = blockIdx.x * 32;
  int k0 = blockIdx.y * 32;
  int tx = threadIdx.x & 31, ty = threadIdx.x >> 5;
#pragma unroll
  for (int r = 0; r < 4; ++r)
    t[ty + r * 8][tx] = W[(size_t)(k0 + ty + r * 8) * N3 + n0 + tx];
  __syncthreads();
#pragma unroll
  for (int r = 0; r < 4; ++r)
    Wt[(size_t)(n0 + ty + r * 8) * DM + k0 + tx] = f2bf(t[tx][ty + r * 8]);
}

// ---------------- 3) QKV GEMM: xb[8192][1024] @ Wt^T -> qk packed + vt transposed ----
// nt<16  -> qk[8192][2048]   (Q cols 0-1023, K cols 1024-2047)
// nt>=16 -> vt[b][d][s]      (V written transposed; k_vt kernel eliminated)
__global__ __launch_bounds__(256, 2) void k_gemm(const u16* __restrict__ xb,
                                                 const u16* __restrict__ wt,
                                                 u16* __restrict__ qk,
                                                 u16* __restrict__ vt) {
  __shared__ u16 As[2][128 * 32];
  __shared__ u16 Bs[2][128 * 32];
  int mt = blockIdx.x / 24, nt = blockIdx.x % 24;
  int m0 = mt * 128, n0 = nt * 128;
  int tid = threadIdx.x, lane = tid & 63, wid = tid >> 6;
  int lr = lane & 15, lg = lane >> 4;
  int wm = (wid >> 1) * 64, wn = (wid & 1) * 64;
  int ca = lane >> 2;
  int cb = (lane & 3) * 8;
  f32x4 acc[4][4] = {};
  int p = 0;
  for (int kk = 0; kk < 1024; kk += 32) {
#pragma unroll
    for (int j = 0; j < 2; ++j) {
      int chunk = wid * 2 + j;
      const u16* ga = xb + (size_t)(m0 + chunk * 16 + ca) * 1024 + kk + cb;
      const u16* gb = wt + (size_t)(n0 + chunk * 16 + ca) * 1024 + kk + cb;
      __builtin_amdgcn_global_load_lds((gptr_t)(const void*)ga, (lptr_t)(void*)&As[p][chunk * 512], 16, 0, 0);
      __builtin_amdgcn_global_load_lds((gptr_t)(const void*)gb, (lptr_t)(void*)&Bs[p][chunk * 512], 16, 0, 0);
    }
    __syncthreads();
    bf16x8 af[4], bff[4];
#pragma unroll
    for (int i = 0; i < 4; ++i) af[i] = *(const bf16x8*)&As[p][(wm + i * 16 + lr) * 32 + lg * 8];
#pragma unroll
    for (int j = 0; j < 4; ++j) bff[j] = *(const bf16x8*)&Bs[p][(wn + j * 16 + lr) * 32 + lg * 8];
#pragma unroll
    for (int i = 0; i < 4; ++i)
#pragma unroll
      for (int j = 0; j < 4; ++j)
        acc[i][j] = MFMA16(af[i], bff[j], acc[i][j]);
    __syncthreads();
    p ^= 1;
  }
  if (nt < 16) {
#pragma unroll
    for (int i = 0; i < 4; ++i)
#pragma unroll
      for (int j = 0; j < 4; ++j)
#pragma unroll
        for (int r = 0; r < 4; ++r)
          qk[(size_t)(m0 + wm + i * 16 + lg * 4 + r) * 2048 + n0 + wn + j * 16 + lr] = f2bf(acc[i][j][r]);
  } else {
    int d0 = n0 - 2048;
#pragma unroll
    for (int i = 0; i < 4; ++i)
#pragma unroll
      for (int j = 0; j < 4; ++j)
#pragma unroll
        for (int r = 0; r < 4; ++r) {
          int m = m0 + wm + i * 16 + lg * 4 + r;
          int d = d0 + wn + j * 16 + lr;
          vt[(size_t)((m >> 11) * DM + d) * SB + (m & 2047)] = f2bf(acc[i][j][r]);
        }
  }
}

// ---------------- 4) S = Q K^T / 32, block-triangular (kt >= qt), bf16 ----------------
__global__ __launch_bounds__(256, 2) void k_qkt(const u16* __restrict__ qk,
                                                u16* __restrict__ S) {
  __shared__ u16 As[2][128 * 32];
  __shared__ u16 Bs[2][128 * 32];
  int bid = blockIdx.x;
  int b = bid & 3;
  int pi = bid >> 2;                 // 0..135 -> (qt, kt) with kt >= qt
  int qt = 0;
  while (true) { int cnt = 16 - qt; if (pi < cnt) break; pi -= cnt; ++qt; }
  int kt = qt + pi;
  int m0 = qt * 128, n0 = kt * 128;
  int tid = threadIdx.x, lane = tid & 63, wid = tid >> 6;
  int lr = lane & 15, lg = lane >> 4;
  int wm = (wid >> 1) * 64, wn = (wid & 1) * 64;
  int ca = lane >> 2;
  int cb = (lane & 3) * 8;
  const u16* Qb = qk + (size_t)(b * SB) * 2048;
  f32x4 acc[4][4] = {};
  int p = 0;
  for (int kk = 0; kk < 1024; kk += 32) {
#pragma unroll
    for (int j = 0; j < 2; ++j) {
      int chunk = wid * 2 + j;
      const u16* ga = Qb + (size_t)(m0 + chunk * 16 + ca) * 2048 + kk + cb;          // Q
      const u16* gb = Qb + (size_t)(n0 + chunk * 16 + ca) * 2048 + 1024 + kk + cb;   // K
      __builtin_amdgcn_global_load_lds((gptr_t)(const void*)ga, (lptr_t)(void*)&As[p][chunk * 512], 16, 0, 0);
      __builtin_amdgcn_global_load_lds((gptr_t)(const void*)gb, (lptr_t)(void*)&Bs[p][chunk * 512], 16, 0, 0);
    }
    __syncthreads();
    bf16x8 af[4], bff[4];
#pragma unroll
    for (int i = 0; i < 4; ++i) af[i] = *(const bf16x8*)&As[p][(wm + i * 16 + lr) * 32 + lg * 8];
#pragma unroll
    for (int j = 0; j < 4; ++j) bff[j] = *(const bf16x8*)&Bs[p][(wn + j * 16 + lr) * 32 + lg * 8];
#pragma unroll
    for (int i = 0; i < 4; ++i)
#pragma unroll
      for (int j = 0; j < 4; ++j)
        acc[i][j] = MFMA16(af[i], bff[j], acc[i][j]);
    __syncthreads();
    p ^= 1;
  }
  u16* Sb = S + (size_t)(b * SB) * 2048;
#pragma unroll
  for (int i = 0; i < 4; ++i)
#pragma unroll
    for (int j = 0; j < 4; ++j)
#pragma unroll
      for (int r = 0; r < 4; ++r) {
        int q = m0 + wm + i * 16 + lg * 4 + r;
        int k = n0 + wn + j * 16 + lr;
        float v = acc[i][j][r] * 0.03125f;
        if (k < q) v = -1e30f;         // keep key >= query (anti-causal)
        Sb[(size_t)q * 2048 + k] = f2bf(v);
      }
}

// ---------------- 5) row softmax in-place on S (valid range k >= qt*128) ----------------
__global__ void k_sm(u16* __restrict__ S) {
  __shared__ float rmax[4], rsum[4];
  int row = blockIdx.x;              // b*2048 + q
  int q = row & 2047;
  int k0 = (q >> 7) << 7;
  int len = 2048 - k0;               // multiple of 128
  int tid = threadIdx.x;
  u16* rp = S + (size_t)row * 2048 + k0;
  int nv = len >> 3;
  bool act = tid < nv;
  float v[8];
  float mx = -1e30f;
  if (act) {
    bf16x8 x = *(const bf16x8*)(rp + tid * 8);
#pragma unroll
    for (int j = 0; j < 8; ++j) { v[j] = bf2f((u16)x[j]); mx = fmaxf(mx, v[j]); }
  }
#pragma unroll
  for (int off = 32; off; off >>= 1) mx = fmaxf(mx, __shfl_xor(mx, off, 64));
  int wv = tid >> 6;
  if ((tid & 63) == 0) rmax[wv] = mx;
  __syncthreads();
  mx = fmaxf(fmaxf(rmax[0], rmax[1]), fmaxf(rmax[2], rmax[3]));
  float sum = 0.f;
  if (act) {
#pragma unroll
    for (int j = 0; j < 8; ++j) { v[j] = __expf(v[j] - mx); sum += v[j]; }
  }
#pragma unroll
  for (int off = 32; off; off >>= 1) sum += __shfl_xor(sum, off, 64);
  if ((tid & 63) == 0) rsum[wv] = sum;
  __syncthreads();
  float inv = 1.f / ((rsum[0] + rsum[1]) + (rsum[2] + rsum[3]));
  if (act) {
    bf16x8 o;
#pragma unroll
    for (int j = 0; j < 8; ++j) o[j] = (short)f2bf(v[j] * inv);
    *(bf16x8*)(rp + tid * 8) = o;
  }
}

// ---------------- 6) O = P V, block-triangular variable-K, f32 out ----------------
__global__ __launch_bounds__(256, 2) void k_pv(const u16* __restrict__ P,
                                               const u16* __restrict__ vt,
                                               float* __restrict__ out) {
  __shared__ u16 As[2][128 * 32];
  __shared__ u16 Bs[2][128 * 32];
  int bid = blockIdx.x;
  int qt = bid >> 5;                 // heavy-first (qt=0 has longest K-loop)
  int rem = bid & 31;
  int dt = rem >> 2;
  int b = rem & 3;
  int m0 = qt * 128, n0 = dt * 128;
  int tid = threadIdx.x, lane = tid & 63, wid = tid >> 6;
  int lr = lane & 15, lg = lane >> 4;
  int wm = (wid >> 1) * 64, wn = (wid & 1) * 64;
  int ca = lane >> 2;
  int cb = (lane & 3) * 8;
  const u16* Pb = P + (size_t)(b * SB) * 2048;
  const u16* Vb = vt + (size_t)(b * DM) * 2048;
  f32x4 acc[4][4] = {};
  int p = 0;
  for (int kk = m0; kk < 2048; kk += 32) {
#pragma unroll
    for (int j = 0; j < 2; ++j) {
      int chunk = wid * 2 + j;
      const u16* ga = Pb + (size_t)(m0 + chunk * 16 + ca) * 2048 + kk + cb;
      const u16* gb = Vb + (size_t)(n0 + chunk * 16 + ca) * 2048 + kk + cb;
      __builtin_amdgcn_global_load_lds((gptr_t)(const void*)ga, (lptr_t)(void*)&As[p][chunk * 512], 16, 0, 0);
      __builtin_amdgcn_global_load_lds((gptr_t)(const void*)gb, (lptr_t)(void*)&Bs[p][chunk * 512], 16, 0, 0);
    }
    __syncthreads();
    bf16x8 af[4], bff[4];
#pragma unroll
    for (int i = 0; i < 4; ++i) af[i] = *(const bf16x8*)&As[p][(wm + i * 16 + lr) * 32 + lg * 8];
#pragma unroll
    for (int j = 0; j < 4; ++j) bff[j] = *(const bf16x8*)&Bs[p][(wn + j * 16 + lr) * 32 + lg * 8];
#pragma unroll
    for (int i = 0; i < 4; ++i)
#pragma unroll
      for (int j = 0; j < 4; ++j)
        acc[i][j] = MFMA16(af[i], bff[j], acc[i][j]);
    __syncthreads();
    p ^= 1;
  }
#pragma unroll
  for (int i = 0; i < 4; ++i)
#pragma unroll
    for (int j = 0; j < 4; ++j)
#pragma unroll
      for (int r = 0; r < 4; ++r)
        out[(size_t)(b * SB + m0 + wm + i * 16 + lg * 4 + r) * DM + n0 + wn + j * 16 + lr] = acc[i][j][r];
}

extern "C" void kernel_launch(void* const* d_in, const int* in_sizes, int n_in,
                              void* d_out, int out_size, void* d_ws, size_t ws_size,
                              hipStream_t stream) {
  const float* x = (const float*)d_in[0];
  const float* W = (const float*)d_in[1];
  float* out = (float*)d_out;
  char* ws = (char*)d_ws;
  // layout (80 MB total):
  u16* qk = (u16*)(ws);                  // 32 MB : [8192][2048] bf16 (Q | K)
  u16* vt = (u16*)(ws + 33554432);       // 16 MB : [4][1024][2048] bf16 (V^T)
  u16* xb = (u16*)(ws + 50331648);       // 16 MB : x bf16 (dead after k_gemm)
  u16* wt = (u16*)(ws + 67108864);       //  6 MB : W^T bf16 (dead after k_gemm)
  u16* S  = (u16*)(ws + 50331648);       // 32 MB : scores/P bf16, reuses xb+wt region

  k_cvt_x<<<8192, 256, 0, stream>>>(x, xb, 2097152);
  dim3 gw(96, 32);
  k_cvt_wt<<<gw, 256, 0, stream>>>(W, wt);
  k_gemm<<<1536, 256, 0, stream>>>(xb, wt, qk, vt);
  k_qkt<<<544, 256, 0, stream>>>(qk, S);
  k_sm<<<8192, 256, 0, stream>>>(S);
  k_pv<<<512, 256, 0, stream>>>(S, vt, out);
}